// Round 1
// baseline (7108.416 us; speedup 1.0000x reference)
//
#include <hip/hip_runtime.h>
#include <math.h>

// BayesianCTC on MI355X — round 0: correctness-first decomposition.
//
// Pipeline (all on `stream`, fixed work per call, graph-capture safe):
//  K1 lse_label_kernel : fused GEMM + online logsumexp + gather of 201 label
//                        columns -> lp[B][T][201] (f32 logprobs). Never
//                        materializes the (B,T,2048) logits.
//  K2 scan_kernel      : alpha (role 0) and beta (role 1) CTC recursions,
//                        f64, one block per (batch, role), LDS double-buffer,
//                        one barrier per t-step. Writes alphaU/betaU (B,T,U) f64.
//  K3 loss_kernel      : per (b,u) logsumexp over t of alpha+beta_prime+risk,
//                        exact _log_sub_exp semantics incl. the -2000/-2001
//                        substitution and NaN->NEG.
//  K4 finalize_kernel  : mean over batch -> d_out[0] (f32).
//
// Workspace: alphaU 41MB + betaU 41MB + lossb + lp 20.6MB ~= 103MB.

#define Bn    16
#define Tn    1600
#define NE    512      // EPROJS
#define OD    2048     // ODIM
#define Un    200
#define Sn    401      // 2U+1
#define NLAB  201      // blank + U labels

#define NEGINF (-INFINITY)

// ---------------------------------------------------------------- K1 ------
#define RPB  16        // rows (b,t) per block
#define CGR  16        // column-group threads per row
#define PADF 516       // padded hs-tile row stride (floats); 516%32=4 -> 2-way LDS aliasing (free)

__device__ __forceinline__ float dot512(const float4* __restrict__ a,
                                        const float4* __restrict__ w) {
    float s0 = 0.f, s1 = 0.f, s2 = 0.f, s3 = 0.f;
    #pragma unroll 4
    for (int k = 0; k < 128; k += 4) {
        float4 x0 = a[k+0], y0 = w[k+0];
        float4 x1 = a[k+1], y1 = w[k+1];
        float4 x2 = a[k+2], y2 = w[k+2];
        float4 x3 = a[k+3], y3 = w[k+3];
        s0 += x0.x*y0.x + x0.y*y0.y + x0.z*y0.z + x0.w*y0.w;
        s1 += x1.x*y1.x + x1.y*y1.y + x1.z*y1.z + x1.w*y1.w;
        s2 += x2.x*y2.x + x2.y*y2.y + x2.z*y2.z + x2.w*y2.w;
        s3 += x3.x*y3.x + x3.y*y3.y + x3.z*y3.z + x3.w*y3.w;
    }
    return (s0 + s1) + (s2 + s3);
}

__global__ __launch_bounds__(256)
void lse_label_kernel(const float* __restrict__ hs, const float* __restrict__ W,
                      const float* __restrict__ bias, const int* __restrict__ ys,
                      float* __restrict__ lp_out)
{
    __shared__ float sh[RPB * PADF];
    __shared__ float red_m[RPB][CGR];
    __shared__ float red_s[RPB][CGR];
    __shared__ float lse_sh[RPB];
    __shared__ int   labs[NLAB];

    const int row0 = blockIdx.x * RPB;          // flat row = b*Tn + t
    const int b    = row0 / Tn;                 // 100 blocks per b, never crosses b
    const int tid  = threadIdx.x;

    if (tid < NLAB) {
        int v = 0;
        if (tid > 0) { int y = ys[b * Un + (tid - 1)]; v = (y < 0) ? 0 : y; }
        labs[tid] = v;
    }
    // stage 16x512 hs rows into LDS (coalesced float4)
    const float4* hs4 = (const float4*)(hs + (size_t)row0 * NE);
    for (int i = tid; i < RPB * (NE / 4); i += 256) {
        int r = i >> 7, c4 = i & 127;
        float4 v = hs4[r * 128 + c4];
        float* dst = &sh[r * PADF + c4 * 4];
        dst[0] = v.x; dst[1] = v.y; dst[2] = v.z; dst[3] = v.w;
    }
    __syncthreads();

    const int r  = tid & (RPB - 1);
    const int cc = tid >> 4;
    const float4* shr = (const float4*)(&sh[r * PADF]);

    // online logsumexp over all 2048 columns (128 per thread)
    float m = -INFINITY, s = 0.f;
    for (int col = cc; col < OD; col += CGR) {
        float acc = bias[col] + dot512(shr, (const float4*)(W + (size_t)col * NE));
        if (acc > m) { s = s * __expf(m - acc) + 1.f; m = acc; }
        else         { s += __expf(acc - m); }
    }
    red_m[r][cc] = m; red_s[r][cc] = s;
    __syncthreads();
    if (tid < RPB) {
        float M = -INFINITY;
        #pragma unroll
        for (int j = 0; j < CGR; j++) M = fmaxf(M, red_m[tid][j]);
        float S = 0.f;
        #pragma unroll
        for (int j = 0; j < CGR; j++) S += red_s[tid][j] * __expf(red_m[tid][j] - M);
        lse_sh[tid] = M + __logf(S);
    }
    __syncthreads();

    // gathered label columns: lp[b][t][j] = logit[labs[j]] - lse
    const float lse_r = lse_sh[r];
    for (int j = cc; j < NLAB; j += CGR) {
        int col = labs[j];
        float acc = bias[col] + dot512(shr, (const float4*)(W + (size_t)col * NE));
        lp_out[(size_t)(row0 + r) * NLAB + j] = acc - lse_r;
    }
}

// ---------------------------------------------------------------- K2 ------
__global__ __launch_bounds__(448)
void scan_kernel(const float* __restrict__ lp, const int* __restrict__ hlens,
                 const int* __restrict__ ys, double* __restrict__ alphaU,
                 double* __restrict__ betaU)
{
    __shared__ double buf[2][Sn + 1];
    __shared__ char   allow_s[Sn];
    __shared__ int    sh_olen, sh_hlen;

    const int b    = blockIdx.x & (Bn - 1);
    const int role = blockIdx.x >> 4;     // 0 = alpha, 1 = beta
    const int tid  = threadIdx.x;

    if (tid == 0) {
        int o = 0;
        for (int u = 0; u < Un; u++) if (ys[b * Un + u] >= 0) o++;
        sh_olen = o;
        sh_hlen = hlens[b];
    }
    if (tid < Sn) {
        char a = 0;
        if (tid & 1) {
            int u = tid >> 1;
            if (u > 0) {
                int y0 = ys[b * Un + u - 1]; if (y0 < 0) y0 = 0;
                int y1 = ys[b * Un + u];     if (y1 < 0) y1 = 0;
                a = (y0 != y1);
            }
        }
        allow_s[tid] = a;
        buf[0][tid] = NEGINF;
    }
    __syncthreads();

    const float* lpb = lp + (size_t)b * Tn * NLAB;

    if (role == 0) {
        // ---------------- alpha ----------------
        double* aU = alphaU + (size_t)b * Tn * Un;
        if (tid < Sn) {
            double v = NEGINF;
            if (tid == 0) v = (double)lpb[0];
            else if (tid == 1) v = (double)lpb[1];
            buf[0][tid] = v;
            if (tid & 1) aU[tid >> 1] = v;
        }
        __syncthreads();
        for (int t = 1; t < Tn; t++) {
            const double* cur = buf[(t - 1) & 1];
            double* nxt = buf[t & 1];
            if (tid < Sn) {
                double v0 = cur[tid];
                double v1 = (tid >= 1) ? cur[tid - 1] : NEGINF;
                double v2 = (tid >= 2 && allow_s[tid]) ? cur[tid - 2] : NEGINF;
                double em = (tid & 1) ? (double)lpb[(size_t)t * NLAB + 1 + (tid >> 1)]
                                      : (double)lpb[(size_t)t * NLAB];
                double mx = fmax(v0, fmax(v1, v2));
                double nv;
                if (isinf(mx)) nv = NEGINF;
                else nv = em + mx + log(exp(v0 - mx) + exp(v1 - mx) + exp(v2 - mx));
                nxt[tid] = nv;
                if (tid & 1) aU[(size_t)t * Un + (tid >> 1)] = nv;
            }
            __syncthreads();
        }
    } else {
        // ---------------- beta ----------------
        double* bU = betaU + (size_t)b * Tn * Un;
        const int hlen = sh_hlen, olen = sh_olen;
        for (int t = Tn - 1; t >= 0; t--) {
            const int it = (Tn - 1 - t) & 1;
            const double* cur = buf[it];
            double* nxt = buf[it ^ 1];
            if (tid < Sn) {
                const int te = (t + 1 < Tn) ? t + 1 : Tn - 1;
                const float* lpt = lpb + (size_t)te * NLAB;
                double e0 = (tid & 1) ? (double)lpt[1 + (tid >> 1)] : (double)lpt[0];
                double g0 = e0 + cur[tid];
                double g1 = NEGINF, g2 = NEGINF;
                if (tid + 1 < Sn) {
                    double e1 = ((tid + 1) & 1) ? (double)lpt[1 + ((tid + 1) >> 1)] : (double)lpt[0];
                    g1 = e1 + cur[tid + 1];
                }
                if (tid + 2 < Sn && allow_s[tid + 2]) {
                    double e2 = ((tid + 2) & 1) ? (double)lpt[1 + ((tid + 2) >> 1)] : (double)lpt[0];
                    g2 = e2 + cur[tid + 2];
                }
                double mx = fmax(g0, fmax(g1, g2));
                double nv;
                if (isinf(mx)) nv = NEGINF;
                else nv = mx + log(exp(g0 - mx) + exp(g1 - mx) + exp(g2 - mx));
                if (t == hlen - 1) nv = (tid == 2 * olen || tid == 2 * olen - 1) ? 0.0 : NEGINF;
                nxt[tid] = nv;
                if (tid & 1) bU[(size_t)t * Un + (tid >> 1)] = nv;
            }
            __syncthreads();
        }
    }
}

// ---------------------------------------------------------------- K3 ------
__device__ __forceinline__ double log_sub_exp_ref(double a, double b) {
    bool ia = isinf(a), ib = isinf(b);   // only -inf occurs
    if (!ia && !ib) {
        double tmp = b + log(exp(a - b) - 1.0);
        if (isinf(tmp)) return -2001.0 + log(exp(1.0) - 1.0);  // ref's a_=-2000,b_=-2001 path
        return tmp;                                            // may be NaN (a<b) -> caller maps to NEG
    }
    if (!ia && ib) return a;
    return NEGINF;
}

__global__ __launch_bounds__(256)
void loss_kernel(const float* __restrict__ lp, const int* __restrict__ hlens,
                 const int* __restrict__ ys, const double* __restrict__ alphaU,
                 const double* __restrict__ betaU, double* __restrict__ lossb)
{
    __shared__ double lu[Un];
    __shared__ int sh_olen;
    const int b = blockIdx.x;
    const int tid = threadIdx.x;
    if (tid == 0) {
        int o = 0;
        for (int u = 0; u < Un; u++) if (ys[b * Un + u] >= 0) o++;
        sh_olen = o;
    }
    __syncthreads();
    const int olen = sh_olen;
    const int hlen = hlens[b];
    const double inv_h = 1.0 / (double)hlen;

    if (tid < Un) {
        const int u = tid;
        const double* aU  = alphaU + (size_t)b * Tn * Un + u;
        const double* bU  = betaU  + (size_t)b * Tn * Un + u;
        const float*  lpu = lp + (size_t)b * Tn * NLAB + 1 + u;
        const bool uvalid = (u < olen);
        double m = NEGINF, s = 0.0;
        for (int t = 0; t < Tn; t++) {
            bool vt = uvalid && (t < hlen);
            double a  = vt ? aU[(size_t)t * Un] : NEGINF;
            double bm = vt ? bU[(size_t)t * Un] : NEGINF;
            double bp;
            if (t == Tn - 1) bp = bm;
            else {
                bool vt1 = uvalid && (t + 1 < hlen);
                double bnx = vt1 ? bU[(size_t)(t + 1) * Un] : NEGINF;
                double pnx = vt1 ? (double)lpu[(size_t)(t + 1) * NLAB] : NEGINF;
                bp = log_sub_exp_ref(bm, bnx + pnx);
            }
            double st = a + bp + (double)(t + 1) * inv_h * 0.1;
            if (isnan(st)) st = NEGINF;
            if (!isinf(st)) {
                if (st > m) { s = s * exp(m - st) + 1.0; m = st; }
                else        { s += exp(st - m); }
            }
        }
        lu[u] = (s == 0.0) ? NEGINF : m + log(s);
    }
    __syncthreads();
    if (tid == 0) {
        int cnt = 0;
        for (int u = 0; u < Un; u++) if (!isinf(lu[u])) cnt++;
        int last = cnt - 1; if (last < 0) last = 0;
        double lf = lu[last];
        if (hlen < olen) lf = 0.0;
        lossb[b] = lf;
    }
}

// ---------------------------------------------------------------- K4 ------
__global__ void finalize_kernel(const double* __restrict__ lossb, float* __restrict__ out) {
    if (threadIdx.x == 0 && blockIdx.x == 0) {
        double ssum = 0.0;
        for (int i = 0; i < Bn; i++) ssum += lossb[i];
        out[0] = (float)(-ssum / (double)Bn);
    }
}

// ------------------------------------------------------------- launch -----
extern "C" void kernel_launch(void* const* d_in, const int* in_sizes, int n_in,
                              void* d_out, int out_size, void* d_ws, size_t ws_size,
                              hipStream_t stream) {
    const float* hs    = (const float*)d_in[0];
    const float* W     = (const float*)d_in[1];
    const float* bias  = (const float*)d_in[2];
    const int*   hlens = (const int*)d_in[3];
    const int*   ys    = (const int*)d_in[4];
    // d_in[5] (ali) unused by the loss
    float* out = (float*)d_out;

    double* alphaU = (double*)d_ws;                         // B*T*U f64 = 40.96 MB
    double* betaU  = alphaU + (size_t)Bn * Tn * Un;         // 40.96 MB
    double* lossb  = betaU + (size_t)Bn * Tn * Un;          // 16 f64
    float*  lp     = (float*)(lossb + Bn);                  // B*T*201 f32 = 20.58 MB

    hipLaunchKernelGGL(lse_label_kernel, dim3(Bn * Tn / RPB), dim3(256), 0, stream,
                       hs, W, bias, ys, lp);
    hipLaunchKernelGGL(scan_kernel, dim3(2 * Bn), dim3(448), 0, stream,
                       lp, hlens, ys, alphaU, betaU);
    hipLaunchKernelGGL(loss_kernel, dim3(Bn), dim3(256), 0, stream,
                       lp, hlens, ys, alphaU, betaU, lossb);
    hipLaunchKernelGGL(finalize_kernel, dim3(1), dim3(64), 0, stream, lossb, out);
}

// Round 3
// 5287.157 us; speedup vs baseline: 1.3445x; 1.3445x over previous
//
#include <hip/hip_runtime.h>
#include <math.h>

// BayesianCTC on MI355X — round 2: BISECT round.
// R1 (new GEMM + f32 scans + chunked loss) failed absmax=752 — a logic-sized
// error, not precision drift. This round keeps the new K1 (GEMM rewrite, the
// perf win) and reverts K2/K3/K4 to R0's VERBATIM f64 code (absmax 0.0).
//  - pass  => bug lives in the f32 scan/loss port (fix next round)
//  - fail  => bug lives in K0/K1 (attack directly next round)
// Workspace: Wg/biasg alias the head of alphaU (Wg dead after K1, alphaU
// written only from K2 on) -> total 102.50 MB == R0's proven footprint.

#define Bn    16
#define Tn    1600
#define NE    512      // EPROJS
#define OD    2048     // ODIM
#define Un    200
#define Sn    401      // 2U+1
#define NLAB  201      // blank + U labels
#define NGC   256      // gathered/padded label col count

#define NEGINF (-INFINITY)

// ---------------------------------------------------------------- K0 ------
__global__ __launch_bounds__(256)
void gather_kernel(const float* __restrict__ W, const float* __restrict__ bias,
                   const int* __restrict__ ys, float* __restrict__ Wg,
                   float* __restrict__ biasg)
{
    const int b    = blockIdx.x;   // 16
    const int part = blockIdx.y;   // 4 parts x 64 j
    const int tid  = threadIdx.x;

    #pragma unroll
    for (int i = 0; i < 32; ++i) {
        int flat = tid + i * 256;          // 0..8191  (64 rows x 128 float4)
        int jj   = flat >> 7;
        int q    = flat & 127;
        int j    = part * 64 + jj;
        int col;
        if (j == 0) col = 0;
        else if (j <= Un) { int y = ys[b * Un + j - 1]; col = (y < 0) ? 0 : y; }
        else col = -1;
        float4 v = make_float4(0.f, 0.f, 0.f, 0.f);
        if (col >= 0) v = *(const float4*)&W[(size_t)col * NE + q * 4];
        *(float4*)&Wg[((size_t)b * NGC + j) * NE + q * 4] = v;
    }
    if (tid < 64) {
        int j = part * 64 + tid;
        float bv = 0.f;
        int col;
        if (j == 0) col = 0;
        else if (j <= Un) { int y = ys[b * Un + j - 1]; col = (y < 0) ? 0 : y; }
        else col = -1;
        if (col >= 0) bv = bias[col];
        biasg[b * NGC + j] = bv;
    }
}

// ---------------------------------------------------------------- K1 ------
#define MT    32       // rows per block
#define NTT   128      // cols per N-tile
#define KC    64       // k chunk
#define APAD  36       // shA row stride (floats), 16B-aligned

__device__ __forceinline__ void gemm_tile(const float* __restrict__ hsrow0,
                                          const float* __restrict__ Wbase, int c0,
                                          float (*shA)[APAD], float (*shB)[NTT],
                                          int tid, int tr, int tc,
                                          float (&acc)[4][4])
{
    #pragma unroll
    for (int i = 0; i < 4; ++i)
        #pragma unroll
        for (int j = 0; j < 4; ++j) acc[i][j] = 0.f;

    for (int kc = 0; kc < NE / KC; ++kc) {
        __syncthreads();   // protect previous chunk's/phase's LDS reads
        #pragma unroll
        for (int i = 0; i < 2; ++i) {
            int flat = tid + i * 256;      // 0..511
            int r = flat >> 4, kq = flat & 15;
            float4 v = *(const float4*)(hsrow0 + (size_t)r * NE + kc * KC + kq * 4);
            shA[kq * 4 + 0][r] = v.x; shA[kq * 4 + 1][r] = v.y;
            shA[kq * 4 + 2][r] = v.z; shA[kq * 4 + 3][r] = v.w;
        }
        #pragma unroll
        for (int i = 0; i < 8; ++i) {
            int flat = tid + i * 256;      // 0..2047
            int c = flat >> 4, kq = flat & 15;
            float4 v = *(const float4*)(Wbase + (size_t)(c0 + c) * NE + kc * KC + kq * 4);
            shB[kq * 4 + 0][c] = v.x; shB[kq * 4 + 1][c] = v.y;
            shB[kq * 4 + 2][c] = v.z; shB[kq * 4 + 3][c] = v.w;
        }
        __syncthreads();
        #pragma unroll 8
        for (int k = 0; k < KC; ++k) {
            float4 av = *(const float4*)&shA[k][tr * 4];
            float4 bv = *(const float4*)&shB[k][tc * 4];
            acc[0][0] += av.x * bv.x; acc[0][1] += av.x * bv.y;
            acc[0][2] += av.x * bv.z; acc[0][3] += av.x * bv.w;
            acc[1][0] += av.y * bv.x; acc[1][1] += av.y * bv.y;
            acc[1][2] += av.y * bv.z; acc[1][3] += av.y * bv.w;
            acc[2][0] += av.z * bv.x; acc[2][1] += av.z * bv.y;
            acc[2][2] += av.z * bv.z; acc[2][3] += av.z * bv.w;
            acc[3][0] += av.w * bv.x; acc[3][1] += av.w * bv.y;
            acc[3][2] += av.w * bv.z; acc[3][3] += av.w * bv.w;
        }
    }
}

__global__ __launch_bounds__(256, 3)
void logits_kernel(const float* __restrict__ hs, const float* __restrict__ W,
                   const float* __restrict__ bias, const float* __restrict__ Wg,
                   const float* __restrict__ biasg, float* __restrict__ lp)
{
    __shared__ float shA[KC][APAD];
    __shared__ float shB[KC][NTT];
    __shared__ float redm[MT][33];
    __shared__ float reds[MT][33];
    __shared__ float lse_s[MT];

    const int tid  = threadIdx.x;
    const int tr   = tid >> 5;      // 0..7  -> rows tr*4..tr*4+3
    const int tc   = tid & 31;      // 0..31 -> cols tc*4..tc*4+3
    const int row0 = blockIdx.x * MT;
    const int b    = row0 / Tn;     // 50 blocks per batch, never crosses b
    const float* hsrow0 = hs + (size_t)row0 * NE;

    float m[4], s[4];
    #pragma unroll
    for (int i = 0; i < 4; ++i) { m[i] = NEGINF; s[i] = 0.f; }

    float acc[4][4];
    // ---- 16 LSE tiles over the full 2048 columns ----
    for (int ct = 0; ct < OD / NTT; ++ct) {
        gemm_tile(hsrow0, W, ct * NTT, shA, shB, tid, tr, tc, acc);
        float4 bq = *(const float4*)&bias[ct * NTT + tc * 4];
        float bb[4] = {bq.x, bq.y, bq.z, bq.w};
        #pragma unroll
        for (int i = 0; i < 4; ++i)
            #pragma unroll
            for (int j = 0; j < 4; ++j) {
                float v = acc[i][j] + bb[j];
                if (v > m[i]) { s[i] = s[i] * __expf(m[i] - v) + 1.f; m[i] = v; }
                else          { s[i] += __expf(v - m[i]); }
            }
    }
    // ---- in-block per-row LSE reduce ----
    __syncthreads();
    #pragma unroll
    for (int i = 0; i < 4; ++i) { redm[tr * 4 + i][tc] = m[i]; reds[tr * 4 + i][tc] = s[i]; }
    __syncthreads();
    if (tid < MT) {
        float M = NEGINF;
        #pragma unroll 4
        for (int j = 0; j < 32; ++j) M = fmaxf(M, redm[tid][j]);
        float S = 0.f;
        #pragma unroll 4
        for (int j = 0; j < 32; ++j) S += reds[tid][j] * __expf(redm[tid][j] - M);
        lse_s[tid] = M + __logf(S);
    }
    __syncthreads();
    // ---- 2 label tiles against gathered Wg -> lp ----
    for (int ct = 0; ct < NGC / NTT; ++ct) {
        gemm_tile(hsrow0, Wg + (size_t)b * NGC * NE, ct * NTT, shA, shB, tid, tr, tc, acc);
        float4 bq = *(const float4*)&biasg[b * NGC + ct * NTT + tc * 4];
        float bb[4] = {bq.x, bq.y, bq.z, bq.w};
        #pragma unroll
        for (int i = 0; i < 4; ++i) {
            int row = row0 + tr * 4 + i;
            float lse = lse_s[tr * 4 + i];
            #pragma unroll
            for (int j = 0; j < 4; ++j) {
                int col = ct * NTT + tc * 4 + j;
                if (col < NLAB)
                    lp[(size_t)row * NLAB + col] = acc[i][j] + bb[j] - lse;
            }
        }
    }
}

// ------------------------------------------------- K2 (R0 verbatim, f64) --
__global__ __launch_bounds__(448)
void scan_kernel(const float* __restrict__ lp, const int* __restrict__ hlens,
                 const int* __restrict__ ys, double* __restrict__ alphaU,
                 double* __restrict__ betaU)
{
    __shared__ double buf[2][Sn + 1];
    __shared__ char   allow_s[Sn];
    __shared__ int    sh_olen, sh_hlen;

    const int b    = blockIdx.x & (Bn - 1);
    const int role = blockIdx.x >> 4;     // 0 = alpha, 1 = beta
    const int tid  = threadIdx.x;

    if (tid == 0) {
        int o = 0;
        for (int u = 0; u < Un; u++) if (ys[b * Un + u] >= 0) o++;
        sh_olen = o;
        sh_hlen = hlens[b];
    }
    if (tid < Sn) {
        char a = 0;
        if (tid & 1) {
            int u = tid >> 1;
            if (u > 0) {
                int y0 = ys[b * Un + u - 1]; if (y0 < 0) y0 = 0;
                int y1 = ys[b * Un + u];     if (y1 < 0) y1 = 0;
                a = (y0 != y1);
            }
        }
        allow_s[tid] = a;
        buf[0][tid] = NEGINF;
    }
    __syncthreads();

    const float* lpb = lp + (size_t)b * Tn * NLAB;

    if (role == 0) {
        // ---------------- alpha ----------------
        double* aU = alphaU + (size_t)b * Tn * Un;
        if (tid < Sn) {
            double v = NEGINF;
            if (tid == 0) v = (double)lpb[0];
            else if (tid == 1) v = (double)lpb[1];
            buf[0][tid] = v;
            if (tid & 1) aU[tid >> 1] = v;
        }
        __syncthreads();
        for (int t = 1; t < Tn; t++) {
            const double* cur = buf[(t - 1) & 1];
            double* nxt = buf[t & 1];
            if (tid < Sn) {
                double v0 = cur[tid];
                double v1 = (tid >= 1) ? cur[tid - 1] : NEGINF;
                double v2 = (tid >= 2 && allow_s[tid]) ? cur[tid - 2] : NEGINF;
                double em = (tid & 1) ? (double)lpb[(size_t)t * NLAB + 1 + (tid >> 1)]
                                      : (double)lpb[(size_t)t * NLAB];
                double mx = fmax(v0, fmax(v1, v2));
                double nv;
                if (isinf(mx)) nv = NEGINF;
                else nv = em + mx + log(exp(v0 - mx) + exp(v1 - mx) + exp(v2 - mx));
                nxt[tid] = nv;
                if (tid & 1) aU[(size_t)t * Un + (tid >> 1)] = nv;
            }
            __syncthreads();
        }
    } else {
        // ---------------- beta ----------------
        double* bU = betaU + (size_t)b * Tn * Un;
        const int hlen = sh_hlen, olen = sh_olen;
        for (int t = Tn - 1; t >= 0; t--) {
            const int it = (Tn - 1 - t) & 1;
            const double* cur = buf[it];
            double* nxt = buf[it ^ 1];
            if (tid < Sn) {
                const int te = (t + 1 < Tn) ? t + 1 : Tn - 1;
                const float* lpt = lpb + (size_t)te * NLAB;
                double e0 = (tid & 1) ? (double)lpt[1 + (tid >> 1)] : (double)lpt[0];
                double g0 = e0 + cur[tid];
                double g1 = NEGINF, g2 = NEGINF;
                if (tid + 1 < Sn) {
                    double e1 = ((tid + 1) & 1) ? (double)lpt[1 + ((tid + 1) >> 1)] : (double)lpt[0];
                    g1 = e1 + cur[tid + 1];
                }
                if (tid + 2 < Sn && allow_s[tid + 2]) {
                    double e2 = ((tid + 2) & 1) ? (double)lpt[1 + ((tid + 2) >> 1)] : (double)lpt[0];
                    g2 = e2 + cur[tid + 2];
                }
                double mx = fmax(g0, fmax(g1, g2));
                double nv;
                if (isinf(mx)) nv = NEGINF;
                else nv = mx + log(exp(g0 - mx) + exp(g1 - mx) + exp(g2 - mx));
                if (t == hlen - 1) nv = (tid == 2 * olen || tid == 2 * olen - 1) ? 0.0 : NEGINF;
                nxt[tid] = nv;
                if (tid & 1) bU[(size_t)t * Un + (tid >> 1)] = nv;
            }
            __syncthreads();
        }
    }
}

// ------------------------------------------------- K3 (R0 verbatim, f64) --
__device__ __forceinline__ double log_sub_exp_ref(double a, double b) {
    bool ia = isinf(a), ib = isinf(b);   // only -inf occurs
    if (!ia && !ib) {
        double tmp = b + log(exp(a - b) - 1.0);
        if (isinf(tmp)) return -2001.0 + log(exp(1.0) - 1.0);  // ref's a_=-2000,b_=-2001 path
        return tmp;                                            // may be NaN (a<b) -> caller maps to NEG
    }
    if (!ia && ib) return a;
    return NEGINF;
}

__global__ __launch_bounds__(256)
void loss_kernel(const float* __restrict__ lp, const int* __restrict__ hlens,
                 const int* __restrict__ ys, const double* __restrict__ alphaU,
                 const double* __restrict__ betaU, double* __restrict__ lossb)
{
    __shared__ double lu[Un];
    __shared__ int sh_olen;
    const int b = blockIdx.x;
    const int tid = threadIdx.x;
    if (tid == 0) {
        int o = 0;
        for (int u = 0; u < Un; u++) if (ys[b * Un + u] >= 0) o++;
        sh_olen = o;
    }
    __syncthreads();
    const int olen = sh_olen;
    const int hlen = hlens[b];
    const double inv_h = 1.0 / (double)hlen;

    if (tid < Un) {
        const int u = tid;
        const double* aU  = alphaU + (size_t)b * Tn * Un + u;
        const double* bU  = betaU  + (size_t)b * Tn * Un + u;
        const float*  lpu = lp + (size_t)b * Tn * NLAB + 1 + u;
        const bool uvalid = (u < olen);
        double m = NEGINF, s = 0.0;
        for (int t = 0; t < Tn; t++) {
            bool vt = uvalid && (t < hlen);
            double a  = vt ? aU[(size_t)t * Un] : NEGINF;
            double bm = vt ? bU[(size_t)t * Un] : NEGINF;
            double bp;
            if (t == Tn - 1) bp = bm;
            else {
                bool vt1 = uvalid && (t + 1 < hlen);
                double bnx = vt1 ? bU[(size_t)(t + 1) * Un] : NEGINF;
                double pnx = vt1 ? (double)lpu[(size_t)(t + 1) * NLAB] : NEGINF;
                bp = log_sub_exp_ref(bm, bnx + pnx);
            }
            double st = a + bp + (double)(t + 1) * inv_h * 0.1;
            if (isnan(st)) st = NEGINF;
            if (!isinf(st)) {
                if (st > m) { s = s * exp(m - st) + 1.0; m = st; }
                else        { s += exp(st - m); }
            }
        }
        lu[u] = (s == 0.0) ? NEGINF : m + log(s);
    }
    __syncthreads();
    if (tid == 0) {
        int cnt = 0;
        for (int u = 0; u < Un; u++) if (!isinf(lu[u])) cnt++;
        int last = cnt - 1; if (last < 0) last = 0;
        double lf = lu[last];
        if (hlen < olen) lf = 0.0;
        lossb[b] = lf;
    }
}

// ---------------------------------------------------------------- K4 ------
__global__ void finalize_kernel(const double* __restrict__ lossb, float* __restrict__ out) {
    if (threadIdx.x == 0 && blockIdx.x == 0) {
        double ssum = 0.0;
        for (int i = 0; i < Bn; i++) ssum += lossb[i];
        out[0] = (float)(-ssum / (double)Bn);
    }
}

// ------------------------------------------------------------- launch -----
extern "C" void kernel_launch(void* const* d_in, const int* in_sizes, int n_in,
                              void* d_out, int out_size, void* d_ws, size_t ws_size,
                              hipStream_t stream) {
    const float* hs    = (const float*)d_in[0];
    const float* W     = (const float*)d_in[1];
    const float* bias  = (const float*)d_in[2];
    const int*   hlens = (const int*)d_in[3];
    const int*   ys    = (const int*)d_in[4];
    float* out = (float*)d_out;

    double* alphaU = (double*)d_ws;                          // B*T*U f64 = 40.96 MB
    double* betaU  = alphaU + (size_t)Bn * Tn * Un;          // 40.96 MB
    float*  lp     = (float*)(betaU + (size_t)Bn * Tn * Un); // B*T*201 f32 = 20.58 MB
    double* lossb  = (double*)(lp + (size_t)Bn * Tn * NLAB); // 16 f64
    // Wg/biasg alias the head of alphaU: Wg dead after K1; alphaU written in K2.
    float*  Wg     = (float*)alphaU;                         // B*256*512 f32 = 8.39 MB
    float*  biasg  = Wg + (size_t)Bn * NGC * NE;             // B*256

    hipLaunchKernelGGL(gather_kernel, dim3(Bn, 4), dim3(256), 0, stream,
                       W, bias, ys, Wg, biasg);
    hipLaunchKernelGGL(logits_kernel, dim3(Bn * Tn / MT), dim3(256), 0, stream,
                       hs, W, bias, Wg, biasg, lp);
    hipLaunchKernelGGL(scan_kernel, dim3(2 * Bn), dim3(448), 0, stream,
                       lp, hlens, ys, alphaU, betaU);
    hipLaunchKernelGGL(loss_kernel, dim3(Bn), dim3(256), 0, stream,
                       lp, hlens, ys, alphaU, betaU, lossb);
    hipLaunchKernelGGL(finalize_kernel, dim3(1), dim3(64), 0, stream, lossb, out);
}

// Round 5
// 3466.362 us; speedup vs baseline: 2.0507x; 1.5253x over previous
//
#include <hip/hip_runtime.h>
#include <math.h>

// BayesianCTC on MI355X — round 4: second bisect arm.
// Established: R2 (f32-GEMM K1 + f64 scan/loss) = absmax 0.0. R1/R3 share the
// f32 scan/loss port and both land in the same bf16 error bin (~750) with
// DIFFERENT K1s -> bug is in the f32 scan/loss port (location still unknown).
// R4 = R3's K1-MFMA chain + R0/R2's VERBATIM f64 scan/loss/finalize.
//   pass -> K1-MFMA proven; R5 optimizes scan/loss knowing exactly what's safe
//   fail -> K1-MFMA bug isolated
// Workspace aliasing keeps total at R0's proven 102.5 MB:
//   [0,40.96M)  alphaU f64   <- aliased early by hsb/Wb/Wgb (dead before scan)
//   [40.96,81.92M) betaU f64 <- aliased early by Pm/Ps/lse/biasg (dead before scan)
//   [81.92,102.5M) lp f32 (live throughout), then lossb.

#define Bn    16
#define Tn    1600
#define NE    512
#define OD    2048
#define Un    200
#define Sn    401
#define NLAB  201
#define NGC   256

#define NEGINF (-INFINITY)

typedef short bf8_t  __attribute__((ext_vector_type(8)));   // 8 bf16 in 4 VGPRs
typedef float f32x4  __attribute__((ext_vector_type(4)));

__device__ __forceinline__ unsigned short f2bf(float x) {
    unsigned int u = __float_as_uint(x);
    unsigned int r = (u + 0x7FFFu + ((u >> 16) & 1u)) >> 16;  // RNE
    return (unsigned short)r;
}
__device__ __forceinline__ void lse_merge_v(float& M, float& S, float v) {
    if (v > M) { S = S * __expf(M - v) + 1.f; M = v; }
    else       { S += __expf(v - M); }
}
__device__ __forceinline__ void lse_merge_ms(float& M, float& S, float m2, float s2) {
    if (s2 > 0.f) {
        if (m2 > M) { S = S * __expf(M - m2) + s2; M = m2; }
        else        { S += s2 * __expf(m2 - M); }
    }
}

// ------------------------------------------------------------ casts -------
__global__ __launch_bounds__(256)
void cast_hs_kernel(const float* __restrict__ src, unsigned short* __restrict__ dst, int n8) {
    int i = blockIdx.x * 256 + threadIdx.x;
    if (i >= n8) return;
    const float4* s4 = (const float4*)(src + (size_t)i * 8);
    float4 a = s4[0], b = s4[1];
    uint4 o;
    o.x = f2bf(a.x) | ((unsigned)f2bf(a.y) << 16);
    o.y = f2bf(a.z) | ((unsigned)f2bf(a.w) << 16);
    o.z = f2bf(b.x) | ((unsigned)f2bf(b.y) << 16);
    o.w = f2bf(b.z) | ((unsigned)f2bf(b.w) << 16);
    *(uint4*)(dst + (size_t)i * 8) = o;
}

// --------------------------------------------------------- gather Wg ------
__global__ __launch_bounds__(64)
void gather_kernel(const float* __restrict__ W, const float* __restrict__ bias,
                   const int* __restrict__ ys, unsigned short* __restrict__ Wgb,
                   float* __restrict__ biasg)
{
    const int b = blockIdx.x, j = blockIdx.y, tid = threadIdx.x;
    int col = -1;
    if (j == 0) col = 0;
    else if (j <= Un) { int y = ys[b * Un + j - 1]; col = (y < 0) ? 0 : y; }
    unsigned short* dst = Wgb + ((size_t)b * NGC + j) * NE;
    if (col >= 0) {
        const float* srcc = W + (size_t)col * NE;
        #pragma unroll
        for (int it = 0; it < 8; ++it) dst[tid + it * 64] = f2bf(srcc[tid + it * 64]);
    } else {
        #pragma unroll
        for (int it = 0; it < 8; ++it) dst[tid + it * 64] = 0;
    }
    if (tid == 0) biasg[b * NGC + j] = (col >= 0) ? bias[col] : 0.f;
}

// ------------------------------------------------------- main MFMA GEMM ---
#define KCH  64
#define ASTR 72    // padded k-stride (ushorts)

__global__ __launch_bounds__(256, 2)
void gemm_main_kernel(const unsigned short* __restrict__ hsb,
                      const unsigned short* __restrict__ Wb,
                      const float* __restrict__ bias,
                      float* __restrict__ Pm, float* __restrict__ Ps)
{
    __shared__ union {
        struct { unsigned short A[128 * ASTR]; unsigned short B[128 * ASTR]; } t;
        struct { float m[128 * 33]; float s[128 * 33]; } r;
    } sh;
    const int tid  = threadIdx.x;
    const int lane = tid & 63, w = tid >> 6;
    const int mw = w & 1, nw = w >> 1;
    const int quad = lane >> 4, lc = lane & 15;
    const int row0 = blockIdx.x * 128;
    const int c0   = blockIdx.y * 128;

    f32x4 acc[4][4];
    #pragma unroll
    for (int mi = 0; mi < 4; ++mi)
        #pragma unroll
        for (int ni = 0; ni < 4; ++ni) acc[mi][ni] = (f32x4)0.f;

    for (int kc = 0; kc < NE / KCH; ++kc) {
        __syncthreads();
        #pragma unroll
        for (int i = 0; i < 4; ++i) {
            int idx = tid + i * 256;
            int r = idx >> 3, c8 = idx & 7;
            *(uint4*)&sh.t.A[r * ASTR + c8 * 8] =
                *(const uint4*)&hsb[(size_t)(row0 + r) * NE + kc * KCH + c8 * 8];
            *(uint4*)&sh.t.B[r * ASTR + c8 * 8] =
                *(const uint4*)&Wb[(size_t)(c0 + r) * NE + kc * KCH + c8 * 8];
        }
        __syncthreads();
        #pragma unroll
        for (int ks = 0; ks < 2; ++ks) {
            bf8_t af[4], bg[4];
            #pragma unroll
            for (int mi = 0; mi < 4; ++mi)
                af[mi] = *(const bf8_t*)&sh.t.A[(mw * 64 + mi * 16 + lc) * ASTR + ks * 32 + quad * 8];
            #pragma unroll
            for (int ni = 0; ni < 4; ++ni)
                bg[ni] = *(const bf8_t*)&sh.t.B[(nw * 64 + ni * 16 + lc) * ASTR + ks * 32 + quad * 8];
            #pragma unroll
            for (int mi = 0; mi < 4; ++mi)
                #pragma unroll
                for (int ni = 0; ni < 4; ++ni)
                    acc[mi][ni] = __builtin_amdgcn_mfma_f32_16x16x32_bf16(af[mi], bg[ni], acc[mi][ni], 0, 0, 0);
        }
    }
    __syncthreads();
    float bcol[4];
    #pragma unroll
    for (int ni = 0; ni < 4; ++ni) bcol[ni] = bias[c0 + nw * 64 + ni * 16 + lc];
    #pragma unroll
    for (int mi = 0; mi < 4; ++mi)
        #pragma unroll
        for (int r = 0; r < 4; ++r) {
            float M = NEGINF, S = 0.f;
            #pragma unroll
            for (int ni = 0; ni < 4; ++ni) lse_merge_v(M, S, acc[mi][ni][r] + bcol[ni]);
            int rl = mw * 64 + mi * 16 + quad * 4 + r;
            sh.r.m[rl * 33 + nw * 16 + lc] = M;
            sh.r.s[rl * 33 + nw * 16 + lc] = S;
        }
    __syncthreads();
    if (tid < 128) {
        float M = NEGINF, S = 0.f;
        #pragma unroll 4
        for (int j = 0; j < 32; ++j) lse_merge_ms(M, S, sh.r.m[tid * 33 + j], sh.r.s[tid * 33 + j]);
        Pm[(size_t)blockIdx.y * 25600 + row0 + tid] = M;
        Ps[(size_t)blockIdx.y * 25600 + row0 + tid] = S;
    }
}

// ------------------------------------------------------------ lse reduce --
__global__ __launch_bounds__(256)
void lse_reduce_kernel(const float* __restrict__ Pm, const float* __restrict__ Ps,
                       float* __restrict__ lse)
{
    int row = blockIdx.x * 256 + threadIdx.x;
    float M = NEGINF, S = 0.f;
    #pragma unroll 4
    for (int nt = 0; nt < 16; ++nt)
        lse_merge_ms(M, S, Pm[(size_t)nt * 25600 + row], Ps[(size_t)nt * 25600 + row]);
    lse[row] = M + logf(S);
}

// ------------------------------------------------------- label MFMA GEMM --
__global__ __launch_bounds__(256, 2)
void gemm_label_kernel(const unsigned short* __restrict__ hsb,
                       const unsigned short* __restrict__ Wgb,
                       const float* __restrict__ biasg, const float* __restrict__ lse,
                       float* __restrict__ lp)
{
    __shared__ unsigned short shA[64 * ASTR];
    __shared__ unsigned short shB[128 * ASTR];
    const int tid  = threadIdx.x;
    const int lane = tid & 63, w = tid >> 6;
    const int mw = w & 1, nw = w >> 1;
    const int quad = lane >> 4, lc = lane & 15;
    const int b  = blockIdx.x / 25, mt = blockIdx.x % 25;
    const int r0 = b * Tn + mt * 64;
    const int c0 = blockIdx.y * 128;

    f32x4 acc[2][4];
    #pragma unroll
    for (int mi = 0; mi < 2; ++mi)
        #pragma unroll
        for (int ni = 0; ni < 4; ++ni) acc[mi][ni] = (f32x4)0.f;

    const unsigned short* Wgbb = Wgb + (size_t)b * NGC * NE;
    for (int kc = 0; kc < NE / KCH; ++kc) {
        __syncthreads();
        #pragma unroll
        for (int i = 0; i < 2; ++i) {
            int idx = tid + i * 256;
            int r = idx >> 3, c8 = idx & 7;
            *(uint4*)&shA[r * ASTR + c8 * 8] =
                *(const uint4*)&hsb[(size_t)(r0 + r) * NE + kc * KCH + c8 * 8];
        }
        #pragma unroll
        for (int i = 0; i < 4; ++i) {
            int idx = tid + i * 256;
            int r = idx >> 3, c8 = idx & 7;
            *(uint4*)&shB[r * ASTR + c8 * 8] =
                *(const uint4*)&Wgbb[(size_t)(c0 + r) * NE + kc * KCH + c8 * 8];
        }
        __syncthreads();
        #pragma unroll
        for (int ks = 0; ks < 2; ++ks) {
            bf8_t af[2], bg[4];
            #pragma unroll
            for (int mi = 0; mi < 2; ++mi)
                af[mi] = *(const bf8_t*)&shA[(mw * 32 + mi * 16 + lc) * ASTR + ks * 32 + quad * 8];
            #pragma unroll
            for (int ni = 0; ni < 4; ++ni)
                bg[ni] = *(const bf8_t*)&shB[(nw * 64 + ni * 16 + lc) * ASTR + ks * 32 + quad * 8];
            #pragma unroll
            for (int mi = 0; mi < 2; ++mi)
                #pragma unroll
                for (int ni = 0; ni < 4; ++ni)
                    acc[mi][ni] = __builtin_amdgcn_mfma_f32_16x16x32_bf16(af[mi], bg[ni], acc[mi][ni], 0, 0, 0);
        }
    }
    #pragma unroll
    for (int mi = 0; mi < 2; ++mi)
        #pragma unroll
        for (int r = 0; r < 4; ++r) {
            int row = r0 + mw * 32 + mi * 16 + quad * 4 + r;
            float lsv = lse[row];
            #pragma unroll
            for (int ni = 0; ni < 4; ++ni) {
                int col = c0 + nw * 64 + ni * 16 + lc;
                if (col < NLAB)
                    lp[(size_t)row * NLAB + col] = acc[mi][ni][r] + biasg[b * NGC + col] - lsv;
            }
        }
}

// ------------------------------------------------- K2 (R0 verbatim, f64) --
__global__ __launch_bounds__(448)
void scan_kernel(const float* __restrict__ lp, const int* __restrict__ hlens,
                 const int* __restrict__ ys, double* __restrict__ alphaU,
                 double* __restrict__ betaU)
{
    __shared__ double buf[2][Sn + 1];
    __shared__ char   allow_s[Sn];
    __shared__ int    sh_olen, sh_hlen;

    const int b    = blockIdx.x & (Bn - 1);
    const int role = blockIdx.x >> 4;
    const int tid  = threadIdx.x;

    if (tid == 0) {
        int o = 0;
        for (int u = 0; u < Un; u++) if (ys[b * Un + u] >= 0) o++;
        sh_olen = o;
        sh_hlen = hlens[b];
    }
    if (tid < Sn) {
        char a = 0;
        if (tid & 1) {
            int u = tid >> 1;
            if (u > 0) {
                int y0 = ys[b * Un + u - 1]; if (y0 < 0) y0 = 0;
                int y1 = ys[b * Un + u];     if (y1 < 0) y1 = 0;
                a = (y0 != y1);
            }
        }
        allow_s[tid] = a;
        buf[0][tid] = NEGINF;
    }
    __syncthreads();

    const float* lpb = lp + (size_t)b * Tn * NLAB;

    if (role == 0) {
        double* aU = alphaU + (size_t)b * Tn * Un;
        if (tid < Sn) {
            double v = NEGINF;
            if (tid == 0) v = (double)lpb[0];
            else if (tid == 1) v = (double)lpb[1];
            buf[0][tid] = v;
            if (tid & 1) aU[tid >> 1] = v;
        }
        __syncthreads();
        for (int t = 1; t < Tn; t++) {
            const double* cur = buf[(t - 1) & 1];
            double* nxt = buf[t & 1];
            if (tid < Sn) {
                double v0 = cur[tid];
                double v1 = (tid >= 1) ? cur[tid - 1] : NEGINF;
                double v2 = (tid >= 2 && allow_s[tid]) ? cur[tid - 2] : NEGINF;
                double em = (tid & 1) ? (double)lpb[(size_t)t * NLAB + 1 + (tid >> 1)]
                                      : (double)lpb[(size_t)t * NLAB];
                double mx = fmax(v0, fmax(v1, v2));
                double nv;
                if (isinf(mx)) nv = NEGINF;
                else nv = em + mx + log(exp(v0 - mx) + exp(v1 - mx) + exp(v2 - mx));
                nxt[tid] = nv;
                if (tid & 1) aU[(size_t)t * Un + (tid >> 1)] = nv;
            }
            __syncthreads();
        }
    } else {
        double* bU = betaU + (size_t)b * Tn * Un;
        const int hlen = sh_hlen, olen = sh_olen;
        for (int t = Tn - 1; t >= 0; t--) {
            const int it = (Tn - 1 - t) & 1;
            const double* cur = buf[it];
            double* nxt = buf[it ^ 1];
            if (tid < Sn) {
                const int te = (t + 1 < Tn) ? t + 1 : Tn - 1;
                const float* lpt = lpb + (size_t)te * NLAB;
                double e0 = (tid & 1) ? (double)lpt[1 + (tid >> 1)] : (double)lpt[0];
                double g0 = e0 + cur[tid];
                double g1 = NEGINF, g2 = NEGINF;
                if (tid + 1 < Sn) {
                    double e1 = ((tid + 1) & 1) ? (double)lpt[1 + ((tid + 1) >> 1)] : (double)lpt[0];
                    g1 = e1 + cur[tid + 1];
                }
                if (tid + 2 < Sn && allow_s[tid + 2]) {
                    double e2 = ((tid + 2) & 1) ? (double)lpt[1 + ((tid + 2) >> 1)] : (double)lpt[0];
                    g2 = e2 + cur[tid + 2];
                }
                double mx = fmax(g0, fmax(g1, g2));
                double nv;
                if (isinf(mx)) nv = NEGINF;
                else nv = mx + log(exp(g0 - mx) + exp(g1 - mx) + exp(g2 - mx));
                if (t == hlen - 1) nv = (tid == 2 * olen || tid == 2 * olen - 1) ? 0.0 : NEGINF;
                nxt[tid] = nv;
                if (tid & 1) bU[(size_t)t * Un + (tid >> 1)] = nv;
            }
            __syncthreads();
        }
    }
}

// ------------------------------------------------- K3 (R0 verbatim, f64) --
__device__ __forceinline__ double log_sub_exp_ref(double a, double b) {
    bool ia = isinf(a), ib = isinf(b);
    if (!ia && !ib) {
        double tmp = b + log(exp(a - b) - 1.0);
        if (isinf(tmp)) return -2001.0 + log(exp(1.0) - 1.0);
        return tmp;
    }
    if (!ia && ib) return a;
    return NEGINF;
}

__global__ __launch_bounds__(256)
void loss_kernel(const float* __restrict__ lp, const int* __restrict__ hlens,
                 const int* __restrict__ ys, const double* __restrict__ alphaU,
                 const double* __restrict__ betaU, double* __restrict__ lossb)
{
    __shared__ double lu[Un];
    __shared__ int sh_olen;
    const int b = blockIdx.x;
    const int tid = threadIdx.x;
    if (tid == 0) {
        int o = 0;
        for (int u = 0; u < Un; u++) if (ys[b * Un + u] >= 0) o++;
        sh_olen = o;
    }
    __syncthreads();
    const int olen = sh_olen;
    const int hlen = hlens[b];
    const double inv_h = 1.0 / (double)hlen;

    if (tid < Un) {
        const int u = tid;
        const double* aU  = alphaU + (size_t)b * Tn * Un + u;
        const double* bU  = betaU  + (size_t)b * Tn * Un + u;
        const float*  lpu = lp + (size_t)b * Tn * NLAB + 1 + u;
        const bool uvalid = (u < olen);
        double m = NEGINF, s = 0.0;
        for (int t = 0; t < Tn; t++) {
            bool vt = uvalid && (t < hlen);
            double a  = vt ? aU[(size_t)t * Un] : NEGINF;
            double bm = vt ? bU[(size_t)t * Un] : NEGINF;
            double bp;
            if (t == Tn - 1) bp = bm;
            else {
                bool vt1 = uvalid && (t + 1 < hlen);
                double bnx = vt1 ? bU[(size_t)(t + 1) * Un] : NEGINF;
                double pnx = vt1 ? (double)lpu[(size_t)(t + 1) * NLAB] : NEGINF;
                bp = log_sub_exp_ref(bm, bnx + pnx);
            }
            double st = a + bp + (double)(t + 1) * inv_h * 0.1;
            if (isnan(st)) st = NEGINF;
            if (!isinf(st)) {
                if (st > m) { s = s * exp(m - st) + 1.0; m = st; }
                else        { s += exp(st - m); }
            }
        }
        lu[u] = (s == 0.0) ? NEGINF : m + log(s);
    }
    __syncthreads();
    if (tid == 0) {
        int cnt = 0;
        for (int u = 0; u < Un; u++) if (!isinf(lu[u])) cnt++;
        int last = cnt - 1; if (last < 0) last = 0;
        double lf = lu[last];
        if (hlen < olen) lf = 0.0;
        lossb[b] = lf;
    }
}

// ---------------------------------------------------------------- K4 ------
__global__ void finalize_kernel(const double* __restrict__ lossb, float* __restrict__ out) {
    if (threadIdx.x == 0 && blockIdx.x == 0) {
        double ssum = 0.0;
        for (int i = 0; i < Bn; i++) ssum += lossb[i];
        out[0] = (float)(-ssum / (double)Bn);
    }
}

// ------------------------------------------------------------- launch -----
extern "C" void kernel_launch(void* const* d_in, const int* in_sizes, int n_in,
                              void* d_out, int out_size, void* d_ws, size_t ws_size,
                              hipStream_t stream) {
    const float* hs    = (const float*)d_in[0];
    const float* W     = (const float*)d_in[1];
    const float* bias  = (const float*)d_in[2];
    const int*   hlens = (const int*)d_in[3];
    const int*   ys    = (const int*)d_in[4];
    float* out = (float*)d_out;

    // ---- aliased workspace, total 102.5 MB (== R0's proven footprint) ----
    char* base = (char*)d_ws;
    double* alphaU = (double*)base;                                  // [0, 40.96M)
    double* betaU  = alphaU + (size_t)Bn * Tn * Un;                  // [40.96, 81.92M)
    float*  lp     = (float*)(betaU + (size_t)Bn * Tn * Un);         // [81.92, 102.50M)
    double* lossb  = (double*)(lp + (size_t)Bn * Tn * NLAB);         // +128 B

    // aliases over alphaU (dead before scan_kernel writes alphaU):
    unsigned short* hsb = (unsigned short*)alphaU;                   // 26.2 MB
    unsigned short* Wb  = hsb + (size_t)25600 * NE;                  // 2.1 MB
    unsigned short* Wgb = Wb + (size_t)OD * NE;                      // 4.2 MB  (32.5M < 40.96M)
    // aliases over betaU (dead before scan_kernel writes betaU):
    float* Pm    = (float*)betaU;                                    // 1.64 MB
    float* Ps    = Pm + (size_t)16 * 25600;                          // 1.64 MB
    float* lse   = Ps + (size_t)16 * 25600;                          // 0.10 MB
    float* biasg = lse + 25600;                                      // 16 KB (3.4M < 40.96M)

    hipLaunchKernelGGL(cast_hs_kernel, dim3(6400), dim3(256), 0, stream,
                       hs, hsb, 25600 * NE / 8);
    hipLaunchKernelGGL(cast_hs_kernel, dim3(512), dim3(256), 0, stream,
                       W, Wb, OD * NE / 8);
    hipLaunchKernelGGL(gather_kernel, dim3(Bn, NGC), dim3(64), 0, stream,
                       W, bias, ys, Wgb, biasg);
    hipLaunchKernelGGL(gemm_main_kernel, dim3(200, 16), dim3(256), 0, stream,
                       hsb, Wb, bias, Pm, Ps);
    hipLaunchKernelGGL(lse_reduce_kernel, dim3(100), dim3(256), 0, stream,
                       Pm, Ps, lse);
    hipLaunchKernelGGL(gemm_label_kernel, dim3(400, 2), dim3(256), 0, stream,
                       hsb, Wgb, biasg, lse, lp);
    hipLaunchKernelGGL(scan_kernel, dim3(2 * Bn), dim3(448), 0, stream,
                       lp, hlens, ys, alphaU, betaU);
    hipLaunchKernelGGL(loss_kernel, dim3(Bn), dim3(256), 0, stream,
                       lp, hlens, ys, alphaU, betaU, lossb);
    hipLaunchKernelGGL(finalize_kernel, dim3(1), dim3(64), 0, stream, lossb, out);
}

// Round 8
// 2242.382 us; speedup vs baseline: 3.1700x; 1.5458x over previous
//
#include <hip/hip_runtime.h>
#include <math.h>

// BayesianCTC on MI355X — round 7.
// ROOT CAUSE (R1-R6): the reference loss is dominated by _log_sub_exp's
// -2000.4587 branch, which fires iff the f64 LSE correction c rounds to 0 at
// ulp(g0) (log(sum) < ~-29.1 for |g0|~4000). f32 evaluation widened that
// window to log(sum) < -16.6 -> ~700 error. Fix: beta scan computes
// beta_prime DIRECTLY: bp = LSE(g1,g2) (== log_sub_exp exactly), with an
// explicit f64-faithful collapse classifier on sumlog = h - g0. Loss becomes
// branch-free f32 adds + online LSE. alphaU/betaP stored f32; betaU gone.

#define Bn    16
#define Tn    1600
#define NE    512
#define OD    2048
#define Un    200
#define Sn    401
#define NLAB  201
#define NGC   256

#define NEGINF (-INFINITY)
#define LSE_SUB_CONST_D (-2000.4586751453871)   // -2001 + log(e-1)

typedef short bf8_t  __attribute__((ext_vector_type(8)));
typedef float f32x4  __attribute__((ext_vector_type(4)));

__device__ __forceinline__ unsigned short f2bf(float x) {
    unsigned int u = __float_as_uint(x);
    unsigned int r = (u + 0x7FFFu + ((u >> 16) & 1u)) >> 16;  // RNE
    return (unsigned short)r;
}
__device__ __forceinline__ void lse_merge_v(float& M, float& S, float v) {
    if (v > M) { S = S * __expf(M - v) + 1.f; M = v; }
    else       { S += __expf(v - M); }
}
__device__ __forceinline__ void lse_merge_ms(float& M, float& S, float m2, float s2) {
    if (s2 > 0.f) {
        if (m2 > M) { S = S * __expf(M - m2) + s2; M = m2; }
        else        { S += s2 * __expf(m2 - M); }
    }
}

// ------------------------------------------------------------ casts -------
__global__ __launch_bounds__(256)
void cast_hs_kernel(const float* __restrict__ src, unsigned short* __restrict__ dst, int n8) {
    int i = blockIdx.x * 256 + threadIdx.x;
    if (i >= n8) return;
    const float4* s4 = (const float4*)(src + (size_t)i * 8);
    float4 a = s4[0], b = s4[1];
    uint4 o;
    o.x = f2bf(a.x) | ((unsigned)f2bf(a.y) << 16);
    o.y = f2bf(a.z) | ((unsigned)f2bf(a.w) << 16);
    o.z = f2bf(b.x) | ((unsigned)f2bf(b.y) << 16);
    o.w = f2bf(b.z) | ((unsigned)f2bf(b.w) << 16);
    *(uint4*)(dst + (size_t)i * 8) = o;
}

// --------------------------------------------------------- gather Wg ------
__global__ __launch_bounds__(64)
void gather_kernel(const float* __restrict__ W, const float* __restrict__ bias,
                   const int* __restrict__ ys, unsigned short* __restrict__ Wgb,
                   float* __restrict__ biasg)
{
    const int b = blockIdx.x, j = blockIdx.y, tid = threadIdx.x;
    int col = -1;
    if (j == 0) col = 0;
    else if (j <= Un) { int y = ys[b * Un + j - 1]; col = (y < 0) ? 0 : y; }
    unsigned short* dst = Wgb + ((size_t)b * NGC + j) * NE;
    if (col >= 0) {
        const float* srcc = W + (size_t)col * NE;
        #pragma unroll
        for (int it = 0; it < 8; ++it) dst[tid + it * 64] = f2bf(srcc[tid + it * 64]);
    } else {
        #pragma unroll
        for (int it = 0; it < 8; ++it) dst[tid + it * 64] = 0;
    }
    if (tid == 0) biasg[b * NGC + j] = (col >= 0) ? bias[col] : 0.f;
}

// ------------------------------------------------------- main MFMA GEMM ---
#define KCH  64
#define ASTR 72

__global__ __launch_bounds__(256, 2)
void gemm_main_kernel(const unsigned short* __restrict__ hsb,
                      const unsigned short* __restrict__ Wb,
                      const float* __restrict__ bias,
                      float* __restrict__ Pm, float* __restrict__ Ps)
{
    __shared__ union {
        struct { unsigned short A[128 * ASTR]; unsigned short B[128 * ASTR]; } t;
        struct { float m[128 * 33]; float s[128 * 33]; } r;
    } sh;
    const int tid  = threadIdx.x;
    const int lane = tid & 63, w = tid >> 6;
    const int mw = w & 1, nw = w >> 1;
    const int quad = lane >> 4, lc = lane & 15;
    const int row0 = blockIdx.x * 128;
    const int c0   = blockIdx.y * 128;

    f32x4 acc[4][4];
    #pragma unroll
    for (int mi = 0; mi < 4; ++mi)
        #pragma unroll
        for (int ni = 0; ni < 4; ++ni) acc[mi][ni] = (f32x4)0.f;

    for (int kc = 0; kc < NE / KCH; ++kc) {
        __syncthreads();
        #pragma unroll
        for (int i = 0; i < 4; ++i) {
            int idx = tid + i * 256;
            int r = idx >> 3, c8 = idx & 7;
            *(uint4*)&sh.t.A[r * ASTR + c8 * 8] =
                *(const uint4*)&hsb[(size_t)(row0 + r) * NE + kc * KCH + c8 * 8];
            *(uint4*)&sh.t.B[r * ASTR + c8 * 8] =
                *(const uint4*)&Wb[(size_t)(c0 + r) * NE + kc * KCH + c8 * 8];
        }
        __syncthreads();
        #pragma unroll
        for (int ks = 0; ks < 2; ++ks) {
            bf8_t af[4], bg[4];
            #pragma unroll
            for (int mi = 0; mi < 4; ++mi)
                af[mi] = *(const bf8_t*)&sh.t.A[(mw * 64 + mi * 16 + lc) * ASTR + ks * 32 + quad * 8];
            #pragma unroll
            for (int ni = 0; ni < 4; ++ni)
                bg[ni] = *(const bf8_t*)&sh.t.B[(nw * 64 + ni * 16 + lc) * ASTR + ks * 32 + quad * 8];
            #pragma unroll
            for (int mi = 0; mi < 4; ++mi)
                #pragma unroll
                for (int ni = 0; ni < 4; ++ni)
                    acc[mi][ni] = __builtin_amdgcn_mfma_f32_16x16x32_bf16(af[mi], bg[ni], acc[mi][ni], 0, 0, 0);
        }
    }
    __syncthreads();
    float bcol[4];
    #pragma unroll
    for (int ni = 0; ni < 4; ++ni) bcol[ni] = bias[c0 + nw * 64 + ni * 16 + lc];
    #pragma unroll
    for (int mi = 0; mi < 4; ++mi)
        #pragma unroll
        for (int r = 0; r < 4; ++r) {
            float M = NEGINF, S = 0.f;
            #pragma unroll
            for (int ni = 0; ni < 4; ++ni) lse_merge_v(M, S, acc[mi][ni][r] + bcol[ni]);
            int rl = mw * 64 + mi * 16 + quad * 4 + r;
            sh.r.m[rl * 33 + nw * 16 + lc] = M;
            sh.r.s[rl * 33 + nw * 16 + lc] = S;
        }
    __syncthreads();
    if (tid < 128) {
        float M = NEGINF, S = 0.f;
        #pragma unroll 4
        for (int j = 0; j < 32; ++j) lse_merge_ms(M, S, sh.r.m[tid * 33 + j], sh.r.s[tid * 33 + j]);
        Pm[(size_t)blockIdx.y * 25600 + row0 + tid] = M;
        Ps[(size_t)blockIdx.y * 25600 + row0 + tid] = S;
    }
}

// ------------------------------------------------------------ lse reduce --
__global__ __launch_bounds__(256)
void lse_reduce_kernel(const float* __restrict__ Pm, const float* __restrict__ Ps,
                       float* __restrict__ lse)
{
    int row = blockIdx.x * 256 + threadIdx.x;
    float M = NEGINF, S = 0.f;
    #pragma unroll 4
    for (int nt = 0; nt < 16; ++nt)
        lse_merge_ms(M, S, Pm[(size_t)nt * 25600 + row], Ps[(size_t)nt * 25600 + row]);
    lse[row] = M + logf(S);
}

// ------------------------------------------------------- label MFMA GEMM --
__global__ __launch_bounds__(256, 2)
void gemm_label_kernel(const unsigned short* __restrict__ hsb,
                       const unsigned short* __restrict__ Wgb,
                       const float* __restrict__ biasg, const float* __restrict__ lse,
                       float* __restrict__ lp)
{
    __shared__ unsigned short shA[64 * ASTR];
    __shared__ unsigned short shB[128 * ASTR];
    const int tid  = threadIdx.x;
    const int lane = tid & 63, w = tid >> 6;
    const int mw = w & 1, nw = w >> 1;
    const int quad = lane >> 4, lc = lane & 15;
    const int b  = blockIdx.x / 25, mt = blockIdx.x % 25;
    const int r0 = b * Tn + mt * 64;
    const int c0 = blockIdx.y * 128;

    f32x4 acc[2][4];
    #pragma unroll
    for (int mi = 0; mi < 2; ++mi)
        #pragma unroll
        for (int ni = 0; ni < 4; ++ni) acc[mi][ni] = (f32x4)0.f;

    const unsigned short* Wgbb = Wgb + (size_t)b * NGC * NE;
    for (int kc = 0; kc < NE / KCH; ++kc) {
        __syncthreads();
        #pragma unroll
        for (int i = 0; i < 2; ++i) {
            int idx = tid + i * 256;
            int r = idx >> 3, c8 = idx & 7;
            *(uint4*)&shA[r * ASTR + c8 * 8] =
                *(const uint4*)&hsb[(size_t)(r0 + r) * NE + kc * KCH + c8 * 8];
        }
        #pragma unroll
        for (int i = 0; i < 4; ++i) {
            int idx = tid + i * 256;
            int r = idx >> 3, c8 = idx & 7;
            *(uint4*)&shB[r * ASTR + c8 * 8] =
                *(const uint4*)&Wgbb[(size_t)(c0 + r) * NE + kc * KCH + c8 * 8];
        }
        __syncthreads();
        #pragma unroll
        for (int ks = 0; ks < 2; ++ks) {
            bf8_t af[2], bg[4];
            #pragma unroll
            for (int mi = 0; mi < 2; ++mi)
                af[mi] = *(const bf8_t*)&shA[(mw * 32 + mi * 16 + lc) * ASTR + ks * 32 + quad * 8];
            #pragma unroll
            for (int ni = 0; ni < 4; ++ni)
                bg[ni] = *(const bf8_t*)&shB[(nw * 64 + ni * 16 + lc) * ASTR + ks * 32 + quad * 8];
            #pragma unroll
            for (int mi = 0; mi < 2; ++mi)
                #pragma unroll
                for (int ni = 0; ni < 4; ++ni)
                    acc[mi][ni] = __builtin_amdgcn_mfma_f32_16x16x32_bf16(af[mi], bg[ni], acc[mi][ni], 0, 0, 0);
        }
    }
    #pragma unroll
    for (int mi = 0; mi < 2; ++mi)
        #pragma unroll
        for (int r = 0; r < 4; ++r) {
            int row = r0 + mw * 32 + mi * 16 + quad * 4 + r;
            float lsv = lse[row];
            #pragma unroll
            for (int ni = 0; ni < 4; ++ni) {
                int col = c0 + nw * 64 + ni * 16 + lc;
                if (col < NLAB)
                    lp[(size_t)row * NLAB + col] = acc[mi][ni][r] + biasg[b * NGC + col] - lsv;
            }
        }
}

// --------- K2: f64 state, f32 HW transcendentals, in-scan beta_prime ------
__global__ __launch_bounds__(448)
void scan_kernel(const float* __restrict__ lp, const int* __restrict__ hlens,
                 const int* __restrict__ ys, float* __restrict__ alphaU,
                 float* __restrict__ betaP)
{
    __shared__ double buf[2][Sn + 1];
    __shared__ char   allow_s[Sn];
    __shared__ int    sh_olen, sh_hlen;

    const int b    = blockIdx.x & (Bn - 1);
    const int role = blockIdx.x >> 4;
    const int tid  = threadIdx.x;

    if (tid == 0) {
        int o = 0;
        for (int u = 0; u < Un; u++) if (ys[b * Un + u] >= 0) o++;
        sh_olen = o;
        sh_hlen = hlens[b];
    }
    if (tid < Sn) {
        char a = 0;
        if (tid & 1) {
            int u = tid >> 1;
            if (u > 0) {
                int y0 = ys[b * Un + u - 1]; if (y0 < 0) y0 = 0;
                int y1 = ys[b * Un + u];     if (y1 < 0) y1 = 0;
                a = (y0 != y1);
            }
        }
        allow_s[tid] = a;
        buf[0][tid] = NEGINF;
    }
    __syncthreads();

    const float* lpb = lp + (size_t)b * Tn * NLAB;

    if (role == 0) {
        // ---------------- alpha (R6 body, f32 stores) ----------------
        float* aU = alphaU + (size_t)b * Tn * Un;
        if (tid < Sn) {
            double v = NEGINF;
            if (tid == 0) v = (double)lpb[0];
            else if (tid == 1) v = (double)lpb[1];
            buf[0][tid] = v;
            if (tid & 1) aU[tid >> 1] = (float)v;
        }
        __syncthreads();
        for (int t = 1; t < Tn; t++) {
            const double* cur = buf[(t - 1) & 1];
            double* nxt = buf[t & 1];
            if (tid < Sn) {
                double v0 = cur[tid];
                double v1 = (tid >= 1) ? cur[tid - 1] : NEGINF;
                double v2 = (tid >= 2 && allow_s[tid]) ? cur[tid - 2] : NEGINF;
                double em = (tid & 1) ? (double)lpb[(size_t)t * NLAB + 1 + (tid >> 1)]
                                      : (double)lpb[(size_t)t * NLAB];
                double mx = fmax(v0, fmax(v1, v2));
                double nv;
                if (isinf(mx)) nv = NEGINF;
                else {
                    float sf = __expf((float)(v0 - mx)) + __expf((float)(v1 - mx))
                             + __expf((float)(v2 - mx));
                    nv = em + mx + (double)__logf(sf);
                }
                nxt[tid] = nv;
                if (tid & 1) aU[(size_t)t * Un + (tid >> 1)] = (float)nv;
            }
            __syncthreads();
        }
    } else {
        // ---------------- beta + in-scan beta_prime ----------------
        float* bP = betaP + (size_t)b * Tn * Un;
        const int hlen = sh_hlen, olen = sh_olen;
        const bool odd = (tid & 1);
        const int u = tid >> 1;
        for (int t = Tn - 1; t >= 0; t--) {
            const int it = (Tn - 1 - t) & 1;
            const double* cur = buf[it];
            double* nxt = buf[it ^ 1];
            if (tid < Sn) {
                const int te = (t + 1 < Tn) ? t + 1 : Tn - 1;
                const float* lpt = lpb + (size_t)te * NLAB;
                double e0 = (tid & 1) ? (double)lpt[1 + (tid >> 1)] : (double)lpt[0];
                double g0 = e0 + cur[tid];
                double g1 = NEGINF, g2 = NEGINF;
                if (tid + 1 < Sn) {
                    double e1 = ((tid + 1) & 1) ? (double)lpt[1 + ((tid + 1) >> 1)] : (double)lpt[0];
                    g1 = e1 + cur[tid + 1];
                }
                if (tid + 2 < Sn && allow_s[tid + 2]) {
                    double e2 = ((tid + 2) & 1) ? (double)lpt[1 + ((tid + 2) >> 1)] : (double)lpt[0];
                    g2 = e2 + cur[tid + 2];
                }
                // h = LSE(g1, g2) == log_sub_exp(beta, continuation) exactly
                double mh = fmax(g1, g2), h;
                if (isinf(mh)) h = NEGINF;
                else h = mh + (double)__logf(__expf((float)(g1 - mh)) + __expf((float)(g2 - mh)));
                double mx = fmax(g0, mh);
                double nv;
                if (isinf(mx)) nv = NEGINF;
                else {
                    float sf = __expf((float)(g0 - mx)) + __expf((float)(g1 - mx))
                             + __expf((float)(g2 - mx));
                    nv = mx + (double)__logf(sf);
                }
                if (t == hlen - 1) nv = (tid == 2 * olen || tid == 2 * olen - 1) ? 0.0 : NEGINF;
                nxt[tid] = nv;
                if (odd) {
                    double bp;
                    if (t >= hlen)            bp = NEGINF;               // masked row
                    else if (t == hlen - 1)   bp = (u == olen - 1) ? 0.0 : NEGINF; // bb=NEG -> bm(fin)
                    else if (u >= olen)       bp = NEGINF;               // masked label
                    else if (isinf(g0))       bp = h;                    // bb=-inf -> bm
                    else if (isinf(h))        bp = LSE_SUB_CONST_D;      // sum==0 -> ref D==0
                    else {
                        double sumlog = h - g0;
                        // ref collapse: c=log1p(sum) rounds to 0 at ulp(g0):
                        //   sum < 2^(max(ilogb(g0)-53, -53))
                        long long gb = (long long)__double_as_longlong(fabs(g0));
                        int k = (int)((gb >> 52) & 0x7FF) - 1023 - 53;
                        if (k < -53) k = -53;
                        if (sumlog > 709.782712893384 ||
                            sumlog < 0.6931471805599453 * (double)k)
                            bp = LSE_SUB_CONST_D;
                        else
                            bp = h;
                    }
                    bP[(size_t)t * Un + u] = (float)bp;
                }
            }
            __syncthreads();
        }
    }
}

// --------------------- K3: branch-free f32 loss ---------------------------
__global__ __launch_bounds__(256)
void loss_kernel(const int* __restrict__ hlens, const int* __restrict__ ys,
                 const float* __restrict__ alphaU, const float* __restrict__ betaP,
                 float* __restrict__ lossb)
{
    __shared__ float lu[Un];
    __shared__ int sh_olen;
    const int b = blockIdx.x;
    const int tid = threadIdx.x;
    if (tid == 0) {
        int o = 0;
        for (int u = 0; u < Un; u++) if (ys[b * Un + u] >= 0) o++;
        sh_olen = o;
    }
    __syncthreads();
    const int olen = sh_olen;
    const int hlen = hlens[b];
    const float risk_c = 0.1f / (float)hlen;

    if (tid < Un) {
        const float* aU = alphaU + (size_t)b * Tn * Un + tid;
        const float* bP = betaP  + (size_t)b * Tn * Un + tid;
        float m = NEGINF, s = 0.f;
        for (int t = 0; t < Tn; t++) {
            // bP is fully masked in-scan: invalid (t,u) -> -inf -> st -> -inf
            float st = aU[(size_t)t * Un] + bP[(size_t)t * Un] + (float)(t + 1) * risk_c;
            if (!isinf(st)) lse_merge_v(m, s, st);
        }
        lu[tid] = (s == 0.f) ? NEGINF : m + __logf(s);
    }
    __syncthreads();
    if (tid == 0) {
        int cnt = 0;
        for (int u = 0; u < Un; u++) if (!isinf(lu[u])) cnt++;
        int last = cnt - 1; if (last < 0) last = 0;
        float lf = lu[last];
        if (hlen < olen) lf = 0.f;
        lossb[b] = lf;
    }
}

// ---------------------------------------------------------------- K4 ------
__global__ void finalize_kernel(const float* __restrict__ lossb, float* __restrict__ out) {
    if (threadIdx.x == 0 && blockIdx.x == 0) {
        float ssum = 0.f;
        for (int i = 0; i < Bn; i++) ssum += lossb[i];
        out[0] = -ssum / (float)Bn;
    }
}

// ------------------------------------------------------------- launch -----
extern "C" void kernel_launch(void* const* d_in, const int* in_sizes, int n_in,
                              void* d_out, int out_size, void* d_ws, size_t ws_size,
                              hipStream_t stream) {
    const float* hs    = (const float*)d_in[0];
    const float* W     = (const float*)d_in[1];
    const float* bias  = (const float*)d_in[2];
    const int*   hlens = (const int*)d_in[3];
    const int*   ys    = (const int*)d_in[4];
    float* out = (float*)d_out;

    // ---- workspace, no aliasing needed: ~97.5 MB < proven 102.5 MB ----
    char* p = (char*)d_ws;
    float* lp     = (float*)p;  p += (size_t)25600 * NLAB * 4;        // 20.58 MB
    float* alphaU = (float*)p;  p += (size_t)Bn * Tn * Un * 4;        // 20.48 MB
    float* betaP  = (float*)p;  p += (size_t)Bn * Tn * Un * 4;        // 20.48 MB
    unsigned short* hsb = (unsigned short*)p; p += (size_t)25600 * NE * 2;    // 26.2 MB
    unsigned short* Wb  = (unsigned short*)p; p += (size_t)OD * NE * 2;       // 2.1 MB
    unsigned short* Wgb = (unsigned short*)p; p += (size_t)Bn * NGC * NE * 2; // 4.2 MB
    float* Pm    = (float*)p;   p += (size_t)16 * 25600 * 4;          // 1.64 MB
    float* Ps    = (float*)p;   p += (size_t)16 * 25600 * 4;          // 1.64 MB
    float* lse   = (float*)p;   p += (size_t)25600 * 4;               // 0.10 MB
    float* biasg = (float*)p;   p += (size_t)Bn * NGC * 4;            // 16 KB
    float* lossb = (float*)p;   p += 256;

    hipLaunchKernelGGL(cast_hs_kernel, dim3(6400), dim3(256), 0, stream,
                       hs, hsb, 25600 * NE / 8);
    hipLaunchKernelGGL(cast_hs_kernel, dim3(512), dim3(256), 0, stream,
                       W, Wb, OD * NE / 8);
    hipLaunchKernelGGL(gather_kernel, dim3(Bn, NGC), dim3(64), 0, stream,
                       W, bias, ys, Wgb, biasg);
    hipLaunchKernelGGL(gemm_main_kernel, dim3(200, 16), dim3(256), 0, stream,
                       hsb, Wb, bias, Pm, Ps);
    hipLaunchKernelGGL(lse_reduce_kernel, dim3(100), dim3(256), 0, stream,
                       Pm, Ps, lse);
    hipLaunchKernelGGL(gemm_label_kernel, dim3(400, 2), dim3(256), 0, stream,
                       hsb, Wgb, biasg, lse, lp);
    hipLaunchKernelGGL(scan_kernel, dim3(2 * Bn), dim3(448), 0, stream,
                       lp, hlens, ys, alphaU, betaP);
    hipLaunchKernelGGL(loss_kernel, dim3(Bn), dim3(256), 0, stream,
                       hlens, ys, alphaU, betaP, lossb);
    hipLaunchKernelGGL(finalize_kernel, dim3(1), dim3(64), 0, stream, lossb, out);
}